// Round 4
// baseline (188.466 us; speedup 1.0000x reference)
//
#include <hip/hip_runtime.h>

// Point-transformer block, fp32 with bf16-MFMA for the pairwise pos-MLP
// layer-2. One block per group (B*G = 16384), 256 threads (4 waves).
//
// R3 structure:
//   e_raw[p][0:3]  = relu(a1[i]-a2[j]) @ W2          (p = i*16+j)
//   ea   [p][0:12] = relu(a1[i]-a2[j]) @ (W2@aw1)
// computed as ONE bf16 MFMA pass (M=256,K=64,N=15) -> 8 mfma/wave.
// Softmax uses DPP row_ror reductions (16-lane rows == j-groups), no
// max-subtraction (|sim| small, fp32 exp2 safe).

#define ASTRIDE 68   // a-table row stride (floats)
#define ESTRIDE 264  // e-table row stride (floats), n-major [16][264]
#define BSTRIDE 72   // Bc row stride (shorts), n-major [16][72]

typedef float f32x4v __attribute__((ext_vector_type(4)));
typedef short s16x8  __attribute__((ext_vector_type(8)));

union AFrag { int i[4]; s16x8 s; };

__device__ __forceinline__ unsigned short f2bf_rne(float f) {
    unsigned u = __builtin_bit_cast(unsigned, f);
    u += 0x7fffu + ((u >> 16) & 1u);
    return (unsigned short)(u >> 16);
}

// pack two f32 -> (hi.bf16 << 16) | lo.bf16, truncation (1 v_perm)
__device__ __forceinline__ int pack_bf2(float lo, float hi) {
    return __builtin_amdgcn_perm(__builtin_bit_cast(int, hi),
                                 __builtin_bit_cast(int, lo), 0x07060302);
}

// sum across the 16-lane DPP row via row_ror 1,2,4,8 (all lanes get total)
__device__ __forceinline__ float dpp_add16(float x) {
    float s = x;
    int t;
    t = __builtin_amdgcn_update_dpp(0, __builtin_bit_cast(int, s), 0x121, 0xf, 0xf, false);
    s += __builtin_bit_cast(float, t);
    t = __builtin_amdgcn_update_dpp(0, __builtin_bit_cast(int, s), 0x122, 0xf, 0xf, false);
    s += __builtin_bit_cast(float, t);
    t = __builtin_amdgcn_update_dpp(0, __builtin_bit_cast(int, s), 0x124, 0xf, 0xf, false);
    s += __builtin_bit_cast(float, t);
    t = __builtin_amdgcn_update_dpp(0, __builtin_bit_cast(int, s), 0x128, 0xf, 0xf, false);
    s += __builtin_bit_cast(float, t);
    return s;
}

__global__ __launch_bounds__(256) void pt_main(
    const float* __restrict__ data,     // (BG, 16, 3)
    const float* __restrict__ wqkv,     // (3, 9)
    const float* __restrict__ pw1,      // (3, 64)
    const float* __restrict__ pb1,      // (64)
    const float* __restrict__ pw2,      // (64, 3)
    const float* __restrict__ pb2,      // (3)
    const float* __restrict__ aw1,      // (3, 12)
    const float* __restrict__ ab1,      // (12)
    const float* __restrict__ aw2,      // (12, 3)
    const float* __restrict__ ab2,      // (3)
    const float* __restrict__ mw1,      // (48, 48)
    const float* __restrict__ mb1,      // (48)
    const float* __restrict__ mw2,      // (48, 48)
    const float* __restrict__ mb2,      // (48)
    const float* __restrict__ mw3,      // (48, 1)
    const float* __restrict__ mb3,      // (1)
    float* __restrict__ out)            // (BG)
{
    __shared__ __attribute__((aligned(16))) float s_pos[48];
    __shared__ __attribute__((aligned(16))) float s_q[48], s_k[48], s_v[48];
    __shared__ __attribute__((aligned(16))) float s_qa[16*12], s_ka[16*12];
    __shared__ __attribute__((aligned(16))) float s_sa[48], s_h1[48];
    __shared__ __attribute__((aligned(16))) float a1[16*ASTRIDE], a2[16*ASTRIDE];
    __shared__ __attribute__((aligned(16))) unsigned short s_Bc[16*BSTRIDE];
    __shared__ __attribute__((aligned(16))) float s_e[16*ESTRIDE];

    const int g    = blockIdx.x;
    const int t    = threadIdx.x;
    const int lane = t & 63;
    const int wv   = t >> 6;
    const int quad = lane >> 4;
    const int ln   = lane & 15;

    // ---- phase 0 ----
    if (t < 48) s_pos[t] = data[g * 48 + t];
    __syncthreads();

    // ---- phase 1a: qkv (threads 0..47; v gets +pb2 folded) ----
    if (t < 48) {
        const int sec = t >> 4, p = t & 15;
        const float x0 = s_pos[p*3+0], x1 = s_pos[p*3+1], x2 = s_pos[p*3+2];
        float* dst = (sec == 0) ? s_q : (sec == 1) ? s_k : s_v;
        #pragma unroll
        for (int c = 0; c < 3; ++c) {
            float v = fmaf(x0, wqkv[0*9 + sec*3 + c],
                      fmaf(x1, wqkv[1*9 + sec*3 + c],
                      x2 * wqkv[2*9 + sec*3 + c]));
            if (sec == 2) v += pb2[c];
            dst[p*3+c] = v;
        }
    }

    // ---- phase 1a: a-tables (all 256 threads, 4 h each) ----
    {
        const int ii = t >> 4;
        const int hc = (t & 15) << 2;
        const float x0 = s_pos[ii*3+0], x1 = s_pos[ii*3+1], x2 = s_pos[ii*3+2];
        float4 va, vb;
        #pragma unroll
        for (int c = 0; c < 4; ++c) {
            const int h = hc + c;
            const float s = fmaf(x0, pw1[h], fmaf(x1, pw1[64+h], x2 * pw1[128+h]));
            (&vb.x)[c] = s;            // j side (no bias)
            (&va.x)[c] = s + pb1[h];   // i side (+b1)
        }
        *(float4*)&a1[ii * ASTRIDE + hc] = va;
        *(float4*)&a2[ii * ASTRIDE + hc] = vb;
    }

    // ---- phase 1a: Bc = [W2 | W2@aw1 | 0] in bf16, n-major (all threads) ----
    {
        const int k  = t & 63;
        const int n0 = (t >> 6) << 2;
        const float w0 = pw2[k*3+0], w1 = pw2[k*3+1], w2v = pw2[k*3+2];
        #pragma unroll
        for (int d = 0; d < 4; ++d) {
            const int n = n0 + d;
            float val;
            if (n < 3)       val = (n == 0) ? w0 : (n == 1) ? w1 : w2v;
            else if (n < 15) { const int a = n - 3;
                               val = fmaf(w0, aw1[a], fmaf(w1, aw1[12+a], w2v * aw1[24+a])); }
            else             val = 0.0f;
            s_Bc[n * BSTRIDE + k] = f2bf_rne(val);
        }
    }
    __syncthreads();

    // ---- phase 1b: qa/ka tables (wave 0; consumed after next barrier) ----
    if (t < 32) {
        const int p = t & 15;
        const float* src = (t < 16) ? s_q : s_k;
        const float x0 = src[p*3+0], x1 = src[p*3+1], x2 = src[p*3+2];
        float* dst = (t < 16) ? s_qa : s_ka;
        #pragma unroll
        for (int gg = 0; gg < 12; ++gg) {
            float v = fmaf(x0, aw1[gg], fmaf(x1, aw1[12+gg], x2 * aw1[24+gg]));
            if (t < 16)
                v += fmaf(pb2[0], aw1[gg], fmaf(pb2[1], aw1[12+gg], pb2[2]*aw1[24+gg])) + ab1[gg];
            dst[p*12+gg] = v;
        }
    }

    // ---- phase 2a: MFMA pass. wave wv handles pairs [64wv, 64wv+64) ----
    s16x8 bfrag0 = *(const s16x8*)&s_Bc[ln * BSTRIDE + quad * 8];
    s16x8 bfrag1 = *(const s16x8*)&s_Bc[ln * BSTRIDE + 32 + quad * 8];

    #pragma unroll
    for (int tau = 0; tau < 4; ++tau) {
        const int it = (wv << 2) + tau;          // query index i for this tile
        f32x4v acc = {0.f, 0.f, 0.f, 0.f};
        #pragma unroll
        for (int kc = 0; kc < 2; ++kc) {
            const int off = kc * 32 + quad * 8;
            const float4 u0 = *(const float4*)&a1[it * ASTRIDE + off];
            const float4 u1 = *(const float4*)&a1[it * ASTRIDE + off + 4];
            const float4 w0 = *(const float4*)&a2[ln * ASTRIDE + off];
            const float4 w1 = *(const float4*)&a2[ln * ASTRIDE + off + 4];
            const float r0 = fmaxf(u0.x - w0.x, 0.f);
            const float r1 = fmaxf(u0.y - w0.y, 0.f);
            const float r2 = fmaxf(u0.z - w0.z, 0.f);
            const float r3 = fmaxf(u0.w - w0.w, 0.f);
            const float r4 = fmaxf(u1.x - w1.x, 0.f);
            const float r5 = fmaxf(u1.y - w1.y, 0.f);
            const float r6 = fmaxf(u1.z - w1.z, 0.f);
            const float r7 = fmaxf(u1.w - w1.w, 0.f);
            AFrag af;
            af.i[0] = pack_bf2(r0, r1);
            af.i[1] = pack_bf2(r2, r3);
            af.i[2] = pack_bf2(r4, r5);
            af.i[3] = pack_bf2(r6, r7);
            acc = __builtin_amdgcn_mfma_f32_16x16x32_bf16(
                      af.s, (kc == 0) ? bfrag0 : bfrag1, acc, 0, 0, 0);
        }
        // C: row m = quad*4+reg -> pair p = wv*64 + tau*16 + quad*4 + reg,
        //    col n = ln. n-major store, 4 consecutive p per lane = b128.
        *(f32x4v*)&s_e[ln * ESTRIDE + (wv << 6) + (tau << 4) + (quad << 2)] = acc;
    }
    __syncthreads();

    // ---- phase 2b: per-pair attn (p = t, i = p>>4, j = p&15) ----
    const int i = t >> 4, j = t & 15;

    union F12 { float4 v[3]; float f[12]; } qa_, ka_;
    qa_.v[0] = *(const float4*)&s_qa[i*12 + 0];
    qa_.v[1] = *(const float4*)&s_qa[i*12 + 4];
    qa_.v[2] = *(const float4*)&s_qa[i*12 + 8];
    ka_.v[0] = *(const float4*)&s_ka[j*12 + 0];
    ka_.v[1] = *(const float4*)&s_ka[j*12 + 4];
    ka_.v[2] = *(const float4*)&s_ka[j*12 + 8];

    const float e0 = s_e[0*ESTRIDE + t];
    const float e1 = s_e[1*ESTRIDE + t];
    const float e2 = s_e[2*ESTRIDE + t];
    const float vi0 = s_v[j*3+0] + e0;
    const float vi1 = s_v[j*3+1] + e1;
    const float vi2 = s_v[j*3+2] + e2;

    float m0 = ab2[0], m1 = ab2[1], m2 = ab2[2];
    #pragma unroll
    for (int gg = 0; gg < 12; ++gg) {
        const float hg = fmaxf(qa_.f[gg] - ka_.f[gg] + s_e[(3+gg)*ESTRIDE + t], 0.f);
        m0 = fmaf(hg, aw2[gg*3+0], m0);
        m1 = fmaf(hg, aw2[gg*3+1], m1);
        m2 = fmaf(hg, aw2[gg*3+2], m2);
    }

    // ---- softmax over j (DPP row reductions; no max-sub needed) ----
    const float L2E = 1.44269504f;
    const float p0 = __builtin_amdgcn_exp2f(m0 * L2E);
    const float p1 = __builtin_amdgcn_exp2f(m1 * L2E);
    const float p2 = __builtin_amdgcn_exp2f(m2 * L2E);

    const float n0 = dpp_add16(p0 * vi0);
    const float n1 = dpp_add16(p1 * vi1);
    const float n2 = dpp_add16(p2 * vi2);
    const float d0 = dpp_add16(p0);
    const float d1 = dpp_add16(p1);
    const float d2 = dpp_add16(p2);

    if (j == 0) {
        s_sa[i*3+0] = n0 * __builtin_amdgcn_rcpf(d0);
        s_sa[i*3+1] = n1 * __builtin_amdgcn_rcpf(d1);
        s_sa[i*3+2] = n2 * __builtin_amdgcn_rcpf(d2);
    }
    __syncthreads();

    // ---- phase 3: MLP 48 -> 48 -> 48 -> 1 ----
    if (t < 48) {
        float h1 = mb1[t];
        #pragma unroll
        for (int c = 0; c < 48; ++c) h1 = fmaf(s_sa[c], mw1[c*48+t], h1);
        s_h1[t] = fmaxf(h1, 0.0f);
    }
    __syncthreads();

    float fv = 0.0f;
    if (t < 48) {
        float h2 = mb2[t];
        #pragma unroll
        for (int c = 0; c < 48; ++c) h2 = fmaf(s_h1[c], mw2[c*48+t], h2);
        h2 = fmaxf(h2, 0.0f);
        fv = h2 * mw3[t];
    }
    if (t < 64) {
        #pragma unroll
        for (int mk = 1; mk < 64; mk <<= 1) fv += __shfl_xor(fv, mk);
        if (t == 0) out[g] = fv + mb3[0];
    }
}

extern "C" void kernel_launch(void* const* d_in, const int* in_sizes, int n_in,
                              void* d_out, int out_size, void* d_ws, size_t ws_size,
                              hipStream_t stream) {
    const float* data = (const float*)d_in[1];
    const int groups = out_size;  // B*G = 16384

    pt_main<<<groups, 256, 0, stream>>>(
        data,
        (const float*)d_in[2],  (const float*)d_in[3],  (const float*)d_in[4],
        (const float*)d_in[5],  (const float*)d_in[6],  (const float*)d_in[7],
        (const float*)d_in[8],  (const float*)d_in[9],  (const float*)d_in[10],
        (const float*)d_in[11], (const float*)d_in[12], (const float*)d_in[13],
        (const float*)d_in[14], (const float*)d_in[15], (const float*)d_in[16],
        (float*)d_out);
}

// Round 6
// 143.573 us; speedup vs baseline: 1.3127x; 1.3127x over previous
//
#include <hip/hip_runtime.h>

// Point-transformer block. R5 = R4 with the cvt_pkrtz type fixed
// (__fp16 vec -> bit_cast to _Float16 vec). One block per group
// (B*G = 16384), 256 threads = one per (i,j) pair.

typedef _Float16 h2 __attribute__((ext_vector_type(2)));
typedef _Float16 h8 __attribute__((ext_vector_type(8)));

#define AH_STRIDE 36   // a-table row stride in dwords (32 data + 4 pad)
#define WP_STRIDE 36   // pw2-pair row stride in dwords

union H8U { h8 v; h2 p[4]; unsigned u[4]; };

__device__ __forceinline__ h2 pkrtz(float a, float b) {
    return __builtin_bit_cast(h2, __builtin_amdgcn_cvt_pkrtz(a, b));
}

#if __has_builtin(__builtin_amdgcn_fdot2)
__device__ __forceinline__ float dot2acc(h2 a, h2 b, float c) {
    return __builtin_amdgcn_fdot2(a, b, c, false);
}
#else
__device__ __forceinline__ float dot2acc(h2 a, h2 b, float c) {
    return fmaf((float)a.x, (float)b.x, fmaf((float)a.y, (float)b.y, c));
}
#endif

// sum across the 16-lane DPP row via row_ror 1,2,4,8 (all lanes get total)
__device__ __forceinline__ float dpp_add16(float x) {
    float s = x;
    int t;
    t = __builtin_amdgcn_update_dpp(0, __builtin_bit_cast(int, s), 0x121, 0xf, 0xf, false);
    s += __builtin_bit_cast(float, t);
    t = __builtin_amdgcn_update_dpp(0, __builtin_bit_cast(int, s), 0x122, 0xf, 0xf, false);
    s += __builtin_bit_cast(float, t);
    t = __builtin_amdgcn_update_dpp(0, __builtin_bit_cast(int, s), 0x124, 0xf, 0xf, false);
    s += __builtin_bit_cast(float, t);
    t = __builtin_amdgcn_update_dpp(0, __builtin_bit_cast(int, s), 0x128, 0xf, 0xf, false);
    s += __builtin_bit_cast(float, t);
    return s;
}

__global__ __launch_bounds__(256) void pt_main(
    const float* __restrict__ data,     // (BG, 16, 3)
    const float* __restrict__ wqkv,     // (3, 9)
    const float* __restrict__ pw1,      // (3, 64)
    const float* __restrict__ pb1,      // (64)
    const float* __restrict__ pw2,      // (64, 3)
    const float* __restrict__ pb2,      // (3)
    const float* __restrict__ aw1,      // (3, 12)
    const float* __restrict__ ab1,      // (12)
    const float* __restrict__ aw2,      // (12, 3)
    const float* __restrict__ ab2,      // (3)
    const float* __restrict__ mw1,      // (48, 48)
    const float* __restrict__ mb1,      // (48)
    const float* __restrict__ mw2,      // (48, 48)
    const float* __restrict__ mb2,      // (48)
    const float* __restrict__ mw3,      // (48, 1)
    const float* __restrict__ mb3,      // (1)
    float* __restrict__ out)            // (BG)
{
    __shared__ __attribute__((aligned(16))) float s_pos[48];
    __shared__ __attribute__((aligned(16))) float s_q[48], s_k[48], s_v[48];
    __shared__ __attribute__((aligned(16))) float s_sa[48], s_h1[48];
    __shared__ __attribute__((aligned(16))) unsigned s_a1h[16 * AH_STRIDE]; // f16x2, +pb1
    __shared__ __attribute__((aligned(16))) unsigned s_a2h[16 * AH_STRIDE]; // f16x2
    __shared__ __attribute__((aligned(16))) unsigned s_wp[3 * WP_STRIDE];   // pw2 col pairs

    const int g = blockIdx.x;
    const int t = threadIdx.x;

    // ---- phase 0: load the 16 points (48 floats) ----
    if (t < 48) s_pos[t] = data[g * 48 + t];
    __syncthreads();

    // ---- phase 1a: qkv (threads 0..47) ----
    if (t < 48) {
        const int sec = t >> 4, p = t & 15;
        const float x0 = s_pos[p*3+0], x1 = s_pos[p*3+1], x2 = s_pos[p*3+2];
        float* dst = (sec == 0) ? s_q : (sec == 1) ? s_k : s_v;
        #pragma unroll
        for (int c = 0; c < 3; ++c) {
            dst[p*3+c] = fmaf(x0, wqkv[0*9 + sec*3 + c],
                         fmaf(x1, wqkv[1*9 + sec*3 + c],
                         x2 * wqkv[2*9 + sec*3 + c]));
        }
    }

    // ---- phase 1b: a-tables in packed f16. thread -> point t>>4, 4 h ----
    {
        const int ii = t >> 4;
        const int hc = (t & 15) << 2;      // h base (4 hiddens = 2 pairs)
        const float x0 = s_pos[ii*3+0], x1 = s_pos[ii*3+1], x2 = s_pos[ii*3+2];
        float s[4];
        #pragma unroll
        for (int c = 0; c < 4; ++c) {
            const int h = hc + c;
            s[c] = fmaf(x0, pw1[h], fmaf(x1, pw1[64+h], x2 * pw1[128+h]));
        }
        h2 a1p0 = pkrtz(s[0] + pb1[hc+0], s[1] + pb1[hc+1]);
        h2 a1p1 = pkrtz(s[2] + pb1[hc+2], s[3] + pb1[hc+3]);
        h2 a2p0 = pkrtz(s[0], s[1]);
        h2 a2p1 = pkrtz(s[2], s[3]);
        const int base = ii * AH_STRIDE + (hc >> 1);
        s_a1h[base+0] = __builtin_bit_cast(unsigned, a1p0);
        s_a1h[base+1] = __builtin_bit_cast(unsigned, a1p1);
        s_a2h[base+0] = __builtin_bit_cast(unsigned, a2p0);
        s_a2h[base+1] = __builtin_bit_cast(unsigned, a2p1);
    }

    // ---- phase 1c: pw2 column-pair table (threads 0..95) ----
    if (t < 96) {
        const int hp = t & 31, c = t >> 5;
        h2 wpair = pkrtz(pw2[(2*hp)*3 + c], pw2[(2*hp+1)*3 + c]);
        s_wp[c * WP_STRIDE + hp] = __builtin_bit_cast(unsigned, wpair);
    }
    __syncthreads();

    // ---- phase 2: per-pair. i = t>>4 (broadcast in wave), j = t&15 ----
    const int i = t >> 4, j = t & 15;

    float e0 = pb2[0], e1 = pb2[1], e2 = pb2[2];
    #pragma unroll
    for (int cc = 0; cc < 8; ++cc) {      // 8 hiddens per iter (4 pairs)
        H8U ai, aj, w0, w1, w2;
        ai.v = *(const h8*)&s_a1h[i * AH_STRIDE + cc*4];
        aj.v = *(const h8*)&s_a2h[j * AH_STRIDE + cc*4];
        w0.v = *(const h8*)&s_wp[0 * WP_STRIDE + cc*4];
        w1.v = *(const h8*)&s_wp[1 * WP_STRIDE + cc*4];
        w2.v = *(const h8*)&s_wp[2 * WP_STRIDE + cc*4];
        #pragma unroll
        for (int m = 0; m < 4; ++m) {
            h2 d = ai.p[m] - aj.p[m];               // v_pk_add_f16 (neg)
            h2 z = {(_Float16)0, (_Float16)0};
            h2 r = { d.x > z.x ? d.x : z.x, d.y > z.y ? d.y : z.y };  // v_pk_max
            e0 = dot2acc(r, w0.p[m], e0);
            e1 = dot2acc(r, w1.p[m], e1);
            e2 = dot2acc(r, w2.p[m], e2);
        }
    }

    // v_ij = v[j] + e ; sim input = (q[i]-k[j]) + e
    const float vi0 = s_v[j*3+0] + e0, vi1 = s_v[j*3+1] + e1, vi2 = s_v[j*3+2] + e2;
    const float si0 = s_q[i*3+0] - s_k[j*3+0] + e0;
    const float si1 = s_q[i*3+1] - s_k[j*3+1] + e1;
    const float si2 = s_q[i*3+2] - s_k[j*3+2] + e2;

    // attn-MLP: sim = relu(s_in @ aw1 + ab1) @ aw2 + ab2
    float m0 = ab2[0], m1 = ab2[1], m2 = ab2[2];
    #pragma unroll
    for (int gg = 0; gg < 12; ++gg) {
        float hg = fmaf(si0, aw1[gg], fmaf(si1, aw1[12+gg], fmaf(si2, aw1[24+gg], ab1[gg])));
        hg = fmaxf(hg, 0.0f);
        m0 = fmaf(hg, aw2[gg*3+0], m0);
        m1 = fmaf(hg, aw2[gg*3+1], m1);
        m2 = fmaf(hg, aw2[gg*3+2], m2);
    }

    // ---- softmax over j: DPP row sums, no max-subtraction (R3-validated) ----
    const float L2E = 1.44269504f;
    const float p0 = __builtin_amdgcn_exp2f(m0 * L2E);
    const float p1 = __builtin_amdgcn_exp2f(m1 * L2E);
    const float p2 = __builtin_amdgcn_exp2f(m2 * L2E);

    const float n0 = dpp_add16(p0 * vi0);
    const float n1 = dpp_add16(p1 * vi1);
    const float n2 = dpp_add16(p2 * vi2);
    const float d0 = dpp_add16(p0);
    const float d1 = dpp_add16(p1);
    const float d2 = dpp_add16(p2);

    if (j == 0) {
        s_sa[i*3+0] = n0 * __builtin_amdgcn_rcpf(d0);
        s_sa[i*3+1] = n1 * __builtin_amdgcn_rcpf(d1);
        s_sa[i*3+2] = n2 * __builtin_amdgcn_rcpf(d2);
    }
    __syncthreads();

    // ---- phase 3: MLP 48 -> 48 -> 48 -> 1 ----
    if (t < 48) {
        float h1 = mb1[t];
        #pragma unroll
        for (int c = 0; c < 48; ++c) h1 = fmaf(s_sa[c], mw1[c*48+t], h1);
        s_h1[t] = fmaxf(h1, 0.0f);
    }
    __syncthreads();

    float fv = 0.0f;
    if (t < 48) {
        float h2v = mb2[t];
        #pragma unroll
        for (int c = 0; c < 48; ++c) h2v = fmaf(s_h1[c], mw2[c*48+t], h2v);
        h2v = fmaxf(h2v, 0.0f);
        fv = h2v * mw3[t];
    }
    if (t < 64) {
        #pragma unroll
        for (int mk = 1; mk < 64; mk <<= 1) fv += __shfl_xor(fv, mk);
        if (t == 0) out[g] = fv + mb3[0];
    }
}

extern "C" void kernel_launch(void* const* d_in, const int* in_sizes, int n_in,
                              void* d_out, int out_size, void* d_ws, size_t ws_size,
                              hipStream_t stream) {
    const float* data = (const float*)d_in[1];
    const int groups = out_size;  // B*G = 16384

    pt_main<<<groups, 256, 0, stream>>>(
        data,
        (const float*)d_in[2],  (const float*)d_in[3],  (const float*)d_in[4],
        (const float*)d_in[5],  (const float*)d_in[6],  (const float*)d_in[7],
        (const float*)d_in[8],  (const float*)d_in[9],  (const float*)d_in[10],
        (const float*)d_in[11], (const float*)d_in[12], (const float*)d_in[13],
        (const float*)d_in[14], (const float*)d_in[15], (const float*)d_in[16],
        (float*)d_out);
}

// Round 7
// 139.299 us; speedup vs baseline: 1.3530x; 1.0307x over previous
//
#include <hip/hip_runtime.h>

// Point-transformer block. R6 = R5 + (1) f16-pair weights packed by a
// pre-kernel into d_ws, read via wave-uniform s_load (SGPR operands),
// (2) packed-f16 attn-MLP (pk_fma/pk_max/dot2), (3) stride-4 q/k/v for
// single ds_read_b128. One block per group (16384), 256 thr = (i,j) pair.

typedef _Float16 h2 __attribute__((ext_vector_type(2)));
typedef _Float16 h8 __attribute__((ext_vector_type(8)));

#define AH_STRIDE 36   // a-table row stride in dwords (32 data + 4 pad)

union H8U { h8 v; h2 p[4]; unsigned u[4]; };

__device__ __forceinline__ h2 pkrtz(float a, float b) {
    return __builtin_bit_cast(h2, __builtin_amdgcn_cvt_pkrtz(a, b));
}
__device__ __forceinline__ h2 uash2(unsigned u) {
    return __builtin_bit_cast(h2, u);
}

#if __has_builtin(__builtin_amdgcn_fdot2)
__device__ __forceinline__ float dot2acc(h2 a, h2 b, float c) {
    return __builtin_amdgcn_fdot2(a, b, c, false);
}
#else
__device__ __forceinline__ float dot2acc(h2 a, h2 b, float c) {
    return fmaf((float)a.x, (float)b.x, fmaf((float)a.y, (float)b.y, c));
}
#endif

// sum across the 16-lane DPP row via row_ror 1,2,4,8 (all lanes get total)
__device__ __forceinline__ float dpp_add16(float x) {
    float s = x;
    int t;
    t = __builtin_amdgcn_update_dpp(0, __builtin_bit_cast(int, s), 0x121, 0xf, 0xf, false);
    s += __builtin_bit_cast(float, t);
    t = __builtin_amdgcn_update_dpp(0, __builtin_bit_cast(int, s), 0x122, 0xf, 0xf, false);
    s += __builtin_bit_cast(float, t);
    t = __builtin_amdgcn_update_dpp(0, __builtin_bit_cast(int, s), 0x124, 0xf, 0xf, false);
    s += __builtin_bit_cast(float, t);
    t = __builtin_amdgcn_update_dpp(0, __builtin_bit_cast(int, s), 0x128, 0xf, 0xf, false);
    s += __builtin_bit_cast(float, t);
    return s;
}

// ---- pre-kernel: pack f16-pair weight tables into workspace ----
// ws[0..95]    pw2 pairs, col-major: ws[c*32+hp] = (pw2[2hp][c], pw2[2hp+1][c])
// ws[96..113]  aw1 pairs: ws[96+r*6+gp] = (aw1[r][2gp], aw1[r][2gp+1])
// ws[114..119] ab1 pairs
// ws[120..137] aw2 pairs: ws[120+gp*3+c] = (aw2[2gp][c], aw2[2gp+1][c])
__global__ void wpack(const float* __restrict__ pw2, const float* __restrict__ aw1,
                      const float* __restrict__ ab1, const float* __restrict__ aw2,
                      unsigned* __restrict__ ws) {
    const int t = threadIdx.x;
    if (t < 96) {
        const int hp = t & 31, c = t >> 5;
        ws[c*32+hp] = __builtin_bit_cast(unsigned, pkrtz(pw2[(2*hp)*3+c], pw2[(2*hp+1)*3+c]));
    } else if (t < 114) {
        const int idx = t - 96, r = idx / 6, gp = idx % 6;
        ws[96+r*6+gp] = __builtin_bit_cast(unsigned, pkrtz(aw1[r*12+2*gp], aw1[r*12+2*gp+1]));
    } else if (t < 120) {
        const int gp = t - 114;
        ws[114+gp] = __builtin_bit_cast(unsigned, pkrtz(ab1[2*gp], ab1[2*gp+1]));
    } else if (t < 138) {
        const int idx = t - 120, gp = idx / 3, c = idx % 3;
        ws[120+gp*3+c] = __builtin_bit_cast(unsigned, pkrtz(aw2[(2*gp)*3+c], aw2[(2*gp+1)*3+c]));
    }
}

__global__ __launch_bounds__(256) void pt_main(
    const float* __restrict__ data,     // (BG, 16, 3)
    const float* __restrict__ wqkv,     // (3, 9)
    const float* __restrict__ pw1,      // (3, 64)
    const float* __restrict__ pb1,      // (64)
    const float* __restrict__ pb2,      // (3)
    const float* __restrict__ ab2,      // (3)
    const float* __restrict__ mw1,      // (48, 48)
    const float* __restrict__ mb1,      // (48)
    const float* __restrict__ mw2,      // (48, 48)
    const float* __restrict__ mb2,      // (48)
    const float* __restrict__ mw3,      // (48, 1)
    const float* __restrict__ mb3,      // (1)
    const unsigned* __restrict__ wsp,   // packed f16-pair weights (uniform -> s_load)
    float* __restrict__ out)            // (BG)
{
    __shared__ __attribute__((aligned(16))) float s_pos[48];
    __shared__ __attribute__((aligned(16))) float s_q4[64], s_k4[64], s_v4[64];
    __shared__ __attribute__((aligned(16))) float s_sa[48], s_h1[48];
    __shared__ __attribute__((aligned(16))) unsigned s_a1h[16 * AH_STRIDE]; // f16x2, +pb1
    __shared__ __attribute__((aligned(16))) unsigned s_a2h[16 * AH_STRIDE]; // f16x2

    const int g = blockIdx.x;
    const int t = threadIdx.x;

    // ---- phase 0: load the 16 points (48 floats) ----
    if (t < 48) s_pos[t] = data[g * 48 + t];
    __syncthreads();

    // ---- phase 1a: qkv (threads 0..47), stride-4 layout ----
    if (t < 48) {
        const int sec = t >> 4, p = t & 15;
        const float x0 = s_pos[p*3+0], x1 = s_pos[p*3+1], x2 = s_pos[p*3+2];
        float* dst = (sec == 0) ? s_q4 : (sec == 1) ? s_k4 : s_v4;
        #pragma unroll
        for (int c = 0; c < 3; ++c) {
            dst[p*4+c] = fmaf(x0, wqkv[0*9 + sec*3 + c],
                         fmaf(x1, wqkv[1*9 + sec*3 + c],
                         x2 * wqkv[2*9 + sec*3 + c]));
        }
        dst[p*4+3] = 0.0f;
    }

    // ---- phase 1b: a-tables in packed f16. thread -> point t>>4, 4 h ----
    {
        const int ii = t >> 4;
        const int hc = (t & 15) << 2;      // h base (4 hiddens = 2 pairs)
        const float x0 = s_pos[ii*3+0], x1 = s_pos[ii*3+1], x2 = s_pos[ii*3+2];
        float s[4];
        #pragma unroll
        for (int c = 0; c < 4; ++c) {
            const int h = hc + c;
            s[c] = fmaf(x0, pw1[h], fmaf(x1, pw1[64+h], x2 * pw1[128+h]));
        }
        h2 a1p0 = pkrtz(s[0] + pb1[hc+0], s[1] + pb1[hc+1]);
        h2 a1p1 = pkrtz(s[2] + pb1[hc+2], s[3] + pb1[hc+3]);
        h2 a2p0 = pkrtz(s[0], s[1]);
        h2 a2p1 = pkrtz(s[2], s[3]);
        const int base = ii * AH_STRIDE + (hc >> 1);
        s_a1h[base+0] = __builtin_bit_cast(unsigned, a1p0);
        s_a1h[base+1] = __builtin_bit_cast(unsigned, a1p1);
        s_a2h[base+0] = __builtin_bit_cast(unsigned, a2p0);
        s_a2h[base+1] = __builtin_bit_cast(unsigned, a2p1);
    }
    __syncthreads();

    // ---- phase 2: per-pair. i = t>>4, j = t&15 ----
    const int i = t >> 4, j = t & 15;

    // pos-MLP: e = relu(a1[i]-a2[j]) @ pw2 + pb2 ; weights via SGPR (wsp)
    float e0 = pb2[0], e1 = pb2[1], e2 = pb2[2];
    #pragma unroll
    for (int cc = 0; cc < 8; ++cc) {      // 8 hiddens per iter (4 pairs)
        H8U ai, aj;
        ai.v = *(const h8*)&s_a1h[i * AH_STRIDE + cc*4];
        aj.v = *(const h8*)&s_a2h[j * AH_STRIDE + cc*4];
        #pragma unroll
        for (int m = 0; m < 4; ++m) {
            const int hp = cc*4 + m;                // weight pair index 0..31
            h2 d = ai.p[m] - aj.p[m];               // v_pk_add_f16 (neg)
            h2 z = {(_Float16)0, (_Float16)0};
            h2 r = { d.x > z.x ? d.x : z.x, d.y > z.y ? d.y : z.y };
            e0 = dot2acc(r, uash2(wsp[0*32+hp]), e0);
            e1 = dot2acc(r, uash2(wsp[1*32+hp]), e1);
            e2 = dot2acc(r, uash2(wsp[2*32+hp]), e2);
        }
    }

    // q/k/v single b128 reads
    const float4 qv = *(const float4*)&s_q4[i*4];
    const float4 kv = *(const float4*)&s_k4[j*4];
    const float4 vv = *(const float4*)&s_v4[j*4];
    const float vi0 = vv.x + e0, vi1 = vv.y + e1, vi2 = vv.z + e2;
    const float si0 = qv.x - kv.x + e0;
    const float si1 = qv.y - kv.y + e1;
    const float si2 = qv.z - kv.z + e2;

    // attn-MLP in packed f16: sim = relu(si @ aw1 + ab1) @ aw2 + ab2
    const h2 sx = pkrtz(si0, si0), sy = pkrtz(si1, si1), sz = pkrtz(si2, si2);
    const h2 z2 = {(_Float16)0, (_Float16)0};
    float m0 = ab2[0], m1 = ab2[1], m2 = ab2[2];
    #pragma unroll
    for (int gp = 0; gp < 6; ++gp) {
        h2 acc = uash2(wsp[114+gp]);                                  // ab1 pair
        acc = __builtin_elementwise_fma(sx, uash2(wsp[96+0*6+gp]), acc);
        acc = __builtin_elementwise_fma(sy, uash2(wsp[96+1*6+gp]), acc);
        acc = __builtin_elementwise_fma(sz, uash2(wsp[96+2*6+gp]), acc);
        h2 hg = { acc.x > z2.x ? acc.x : z2.x, acc.y > z2.y ? acc.y : z2.y };
        m0 = dot2acc(hg, uash2(wsp[120+gp*3+0]), m0);
        m1 = dot2acc(hg, uash2(wsp[120+gp*3+1]), m1);
        m2 = dot2acc(hg, uash2(wsp[120+gp*3+2]), m2);
    }

    // ---- softmax over j: DPP row sums, no max-subtraction ----
    const float L2E = 1.44269504f;
    const float p0 = __builtin_amdgcn_exp2f(m0 * L2E);
    const float p1 = __builtin_amdgcn_exp2f(m1 * L2E);
    const float p2 = __builtin_amdgcn_exp2f(m2 * L2E);

    const float n0 = dpp_add16(p0 * vi0);
    const float n1 = dpp_add16(p1 * vi1);
    const float n2 = dpp_add16(p2 * vi2);
    const float d0 = dpp_add16(p0);
    const float d1 = dpp_add16(p1);
    const float d2 = dpp_add16(p2);

    if (j == 0) {
        s_sa[i*3+0] = n0 * __builtin_amdgcn_rcpf(d0);
        s_sa[i*3+1] = n1 * __builtin_amdgcn_rcpf(d1);
        s_sa[i*3+2] = n2 * __builtin_amdgcn_rcpf(d2);
    }
    __syncthreads();

    // ---- phase 3: MLP 48 -> 48 -> 48 -> 1 ----
    if (t < 48) {
        float h1 = mb1[t];
        #pragma unroll
        for (int c = 0; c < 48; ++c) h1 = fmaf(s_sa[c], mw1[c*48+t], h1);
        s_h1[t] = fmaxf(h1, 0.0f);
    }
    __syncthreads();

    float fv = 0.0f;
    if (t < 48) {
        float h2v = mb2[t];
        #pragma unroll
        for (int c = 0; c < 48; ++c) h2v = fmaf(s_h1[c], mw2[c*48+t], h2v);
        h2v = fmaxf(h2v, 0.0f);
        fv = h2v * mw3[t];
    }
    if (t < 64) {
        #pragma unroll
        for (int mk = 1; mk < 64; mk <<= 1) fv += __shfl_xor(fv, mk);
        if (t == 0) out[g] = fv + mb3[0];
    }
}

extern "C" void kernel_launch(void* const* d_in, const int* in_sizes, int n_in,
                              void* d_out, int out_size, void* d_ws, size_t ws_size,
                              hipStream_t stream) {
    const float* data = (const float*)d_in[1];
    unsigned* ws = (unsigned*)d_ws;
    const int groups = out_size;  // B*G = 16384

    wpack<<<1, 256, 0, stream>>>(
        (const float*)d_in[5],   // pw2
        (const float*)d_in[7],   // aw1
        (const float*)d_in[8],   // ab1
        (const float*)d_in[9],   // aw2
        ws);

    pt_main<<<groups, 256, 0, stream>>>(
        data,
        (const float*)d_in[2],   // wqkv
        (const float*)d_in[3],   // pw1
        (const float*)d_in[4],   // pb1
        (const float*)d_in[6],   // pb2
        (const float*)d_in[10],  // ab2
        (const float*)d_in[11],  // mw1
        (const float*)d_in[12],  // mb1
        (const float*)d_in[13],  // mw2
        (const float*)d_in[14],  // mb2
        (const float*)d_in[15],  // mw3
        (const float*)d_in[16],  // mb3
        ws,
        (float*)d_out);
}